// Round 3
// baseline (415.211 us; speedup 1.0000x reference)
//
#include <hip/hip_runtime.h>
#include <cstdint>
#include <cstddef>

typedef __bf16 bf16;
typedef bf16 bf16x2 __attribute__((ext_vector_type(2)));
typedef bf16 bf16x4 __attribute__((ext_vector_type(4)));
typedef bf16 bf16x8 __attribute__((ext_vector_type(8)));
typedef float f32x4 __attribute__((ext_vector_type(4)));

// async global->LDS, 16B per lane; dest must be wave-uniform base (HW adds lane*16)
__device__ __forceinline__ void gll16(const void* g, void* l) {
  __builtin_amdgcn_global_load_lds((__attribute__((address_space(1))) void*)g,
                                   (__attribute__((address_space(3))) void*)l, 16, 0, 0);
}

// ---------------- graph preprocessing ----------------
__global__ void k_init(int* __restrict__ deg, int* __restrict__ cur, int N) {
  int i = blockIdx.x * 256 + threadIdx.x;
  if (i < N) { deg[i] = 1; cur[i] = 0; }   // deg starts at 1: self loop
}

__global__ void k_count(const int* __restrict__ ei, int* __restrict__ deg, int E) {
  int e = blockIdx.x * 256 + threadIdx.x;
  if (e < E) atomicAdd(&deg[ei[E + e]], 1);   // dst = ei[E+e]
}

__global__ __launch_bounds__(256) void k_scan1(const int* __restrict__ deg,
                                               int* __restrict__ bsum, int N) {
  int t = threadIdx.x;
  int i = blockIdx.x * 256 + t;
  int v = (i < N) ? deg[i] - 1 : 0;
#pragma unroll
  for (int off = 32; off > 0; off >>= 1) v += __shfl_down(v, off, 64);
  __shared__ int red[4];
  if ((t & 63) == 0) red[t >> 6] = v;
  __syncthreads();
  if (t == 0) bsum[blockIdx.x] = red[0] + red[1] + red[2] + red[3];
}

__global__ __launch_bounds__(256) void k_scan2(const int* __restrict__ bsum,
                                               int* __restrict__ bpre, int B) {
  __shared__ int s[256];
  int t = threadIdx.x;
  int v = (t < B) ? bsum[t] : 0;
  s[t] = v;
  __syncthreads();
  for (int off = 1; off < 256; off <<= 1) {
    int add = (t >= off) ? s[t - off] : 0;
    __syncthreads();
    s[t] += add;
    __syncthreads();
  }
  if (t < B) bpre[t] = s[t] - v;   // exclusive
}

__global__ __launch_bounds__(256) void k_scan3(const int* __restrict__ deg,
                                               const int* __restrict__ bpre,
                                               int* __restrict__ roff,
                                               float* __restrict__ dinv, int N) {
  __shared__ int s[256];
  int t = threadIdx.x;
  int i = blockIdx.x * 256 + t;
  int d = (i < N) ? deg[i] : 1;
  int v = d - 1;
  if (i >= N) v = 0;
  s[t] = v;
  __syncthreads();
  for (int off = 1; off < 256; off <<= 1) {
    int add = (t >= off) ? s[t - off] : 0;
    __syncthreads();
    s[t] += add;
    __syncthreads();
  }
  if (i < N) {
    int base = bpre[blockIdx.x];
    roff[i] = base + s[t] - v;
    dinv[i] = rsqrtf((float)d);
    if (i == N - 1) roff[N] = base + s[t];
  }
}

__global__ void k_scatter(const int* __restrict__ ei, const int* __restrict__ roff,
                          int* __restrict__ cur, int* __restrict__ csr, int E) {
  int e = blockIdx.x * 256 + threadIdx.x;
  if (e >= E) return;
  int d = ei[E + e];
  int p = atomicAdd(&cur[d], 1);
  csr[roff[d] + p] = ei[e];   // src
}

// ---------------- dtype conversion ----------------
__global__ void k_cvt_x(const float* __restrict__ x, bf16* __restrict__ xb, size_t total) {
  size_t base = ((size_t)blockIdx.x * 256 + threadIdx.x) * 4;
  if (base >= total) return;
  const float4 v = *(const float4*)(x + base);
  bf16x4 o;
  o[0] = (bf16)v.x; o[1] = (bf16)v.y; o[2] = (bf16)v.z; o[3] = (bf16)v.w;
  *(bf16x4*)(xb + base) = o;
}

__global__ void k_cvt_w(const float* __restrict__ W1, const float* __restrict__ W2,
                        const float* __restrict__ Wl, bf16* __restrict__ w1t,
                        bf16* __restrict__ w2t, bf16* __restrict__ wlt) {
  int i = blockIdx.x * 256 + threadIdx.x;   // grid covers 229376 exactly
  if (i < 32768) {
    int n = i >> 7, k = i & 127;
    w1t[i] = (bf16)W1[(size_t)k * 256 + n];
  } else if (i < 163840) {
    int j = i - 32768;
    int n = j >> 8, k = j & 255;
    w2t[j] = (bf16)W2[(size_t)k * 512 + n];
  } else {
    int j = i - 163840;
    int n = j >> 9, k = j & 511;
    wlt[j] = (bf16)Wl[(size_t)k * 128 + n];
  }
}

// ---------------- bf16 MFMA GEMM: C[M,NOUT] = A[M,K] @ Bt[NOUT,K]^T ----------------
// R11 = R10 with the LDS-overlap bug fixed: BN-stats scratch is its own
// __shared__ array (R10 placed it at byte 16384, inside the 32 KiB output
// tile that the epilogue stages in LDS -> rows 64..71 and the stats partials
// corrupted each other; absmax 10.5).
//  - global_load_lds width=16 staging: zero staging VGPRs. XOR row swizzle
//    preserved by pre-swizzling the per-lane GLOBAL source; LDS dest linear
//    (m173). LDS layout slot(j,row)=j*MT+(row^(j<<1)) is byte-identical to
//    R8, so the fragment-read path (measured 0 bank conflicts) is unchanged.
//  - m97 2-buffer schedule: issue(t+1) -> compute buf[t] -> __syncthreads().
//    The barrier's vmcnt(0) drain lands AFTER the compute phase: one K-step
//    of load latency hidden. No inline asm, no raw barriers.
//  - Epilogue via LDS transpose: full 128B-line dwordx4 stores (8/thread)
//    instead of 64 scattered 2B stores (R8's FETCH_SIZE ~= |out| = RFO).
//  - BN stats: per-block plain-stored partials (no 782-deep atomic chains),
//    reduced in k_bnfinal.
// grid = (NOUT/128, Mp/MT): n-stripes sharing an A panel dispatch adjacently.
template<int K, int NOUT, bool FINAL>
__global__ __launch_bounds__(256, 4) void k_gemm(const bf16* __restrict__ A,
                                                 const bf16* __restrict__ Bt,
                                                 bf16* __restrict__ outB,
                                                 float* __restrict__ outF,
                                                 const float* __restrict__ bias,
                                                 float* __restrict__ part,
                                                 int Mreal) {
  constexpr int MT    = FINAL ? 64 : 128;   // m-tile rows
  constexpr int RPW   = MT / 32;            // 16-row subtiles per wave
  constexpr int NSTEP = K / 32;
  constexpr int LMT   = FINAL ? 6 : 7;
  constexpr int SB    = MT * 4 + 512;       // uint4 slots per buffer (A + B)
  constexpr int NAI   = (MT * 4) / 256;     // A DMA issues per thread (2 or 1)
  __shared__ uint4 lds[2 * SB];
  __shared__ float sstm[512];               // stats scratch, DISJOINT from lds

  const int tid = threadIdx.x;
  const int wv = tid >> 6;
  const int lane = tid & 63;
  const int q = lane >> 4, mr = lane & 15;
  const int m0 = blockIdx.y * MT;
  const int n0 = blockIdx.x * 128;
  const int rw = (wv >> 1) * (MT / 2), cw = (wv & 1) * 64;
  const int qs = q << 1;
  const int wslot = wv << 6;

  // pre-swizzled per-lane global sources: dest slot p*256+tid (linear) receives
  // row = sl ^ (j<<1), cols j*8..j*8+7 of the current K-step.
  const bf16* srcA[NAI];
#pragma unroll
  for (int p = 0; p < NAI; ++p) {
    int slot = p * 256 + tid;
    int jj = slot >> LMT, sl = slot & (MT - 1);
    int row = sl ^ (jj << 1);
    srcA[p] = A + (size_t)(m0 + row) * K + jj * 8;
  }
  const bf16* srcB[2];
#pragma unroll
  for (int p = 0; p < 2; ++p) {
    int slot = p * 256 + tid;
    int jj = slot >> 7, sl = slot & 127;
    int row = sl ^ (jj << 1);
    srcB[p] = Bt + (size_t)(n0 + row) * K + jj * 8;
  }

  auto issue = [&](int t) {
    uint4* bb = lds + (t & 1) * SB;
#pragma unroll
    for (int p = 0; p < NAI; ++p)
      gll16(srcA[p] + t * 32, bb + p * 256 + wslot);
#pragma unroll
    for (int p = 0; p < 2; ++p)
      gll16(srcB[p] + t * 32, bb + MT * 4 + p * 256 + wslot);
  };

  f32x4 acc[RPW][4];
#pragma unroll
  for (int r = 0; r < RPW; ++r)
#pragma unroll
    for (int c = 0; c < 4; ++c) acc[r][c] = (f32x4){0.f, 0.f, 0.f, 0.f};

  issue(0);
  __syncthreads();   // drains DMA: buf 0 ready

#pragma unroll
  for (int t = 0; t < NSTEP; ++t) {
    if (t + 1 < NSTEP) issue(t + 1);   // in flight across the compute phase

    const uint4* bb = lds + (t & 1) * SB;
    const bf16x8* bA = (const bf16x8*)bb;
    const bf16x8* bB = (const bf16x8*)(bb + MT * 4);
    bf16x8 bfr[4];
#pragma unroll
    for (int c = 0; c < 4; ++c)
      bfr[c] = bB[q * 128 + ((cw + c * 16 + mr) ^ qs)];
#pragma unroll
    for (int r = 0; r < RPW; ++r) {
      bf16x8 af = bA[q * MT + ((rw + r * 16 + mr) ^ qs)];
#pragma unroll
      for (int c = 0; c < 4; ++c)
        acc[r][c] = __builtin_amdgcn_mfma_f32_16x16x32_bf16(af, bfr[c], acc[r][c], 0, 0, 0);
    }
    __syncthreads();   // drains next tile's DMA (after compute) + read-complete fence
  }

  // C/D layout: col = lane&15, row = (lane>>4)*4 + reg (m89/m91-verified)
  if constexpr (!FINAL) {
    bf16* ot = (bf16*)lds;                  // [128][128] bf16, XOR-swizzled cols
#pragma unroll
    for (int c = 0; c < 4; ++c) {
      float s0 = 0.f, s1 = 0.f;
#pragma unroll
      for (int r = 0; r < RPW; ++r) {
#pragma unroll
        for (int i = 0; i < 4; ++i) {
          int rl = rw + r * 16 + q * 4 + i;
          int cl = cw + c * 16 + mr;
          float v = acc[r][c][i];
          ot[rl * 128 + (cl ^ (((rl >> 2) & 3) << 4))] = (bf16)v;
          if (m0 + rl < Mreal) { s0 += v; s1 += v * v; }
        }
      }
      s0 += __shfl_xor(s0, 16, 64); s0 += __shfl_xor(s0, 32, 64);
      s1 += __shfl_xor(s1, 16, 64); s1 += __shfl_xor(s1, 32, 64);
      if (q == 0) {
        sstm[wv * 64 + c * 16 + mr] = s0;
        sstm[256 + wv * 64 + c * 16 + mr] = s1;
      }
    }
    __syncthreads();
    {
      // combine wave pairs, plain-store per-block partials (no atomics, no zero-init)
      int ssel = tid >> 7, cl = tid & 127;
      int hi = cl >> 6, lo = cl & 63;
      float v = sstm[ssel * 256 + hi * 64 + lo] + sstm[ssel * 256 + (hi + 2) * 64 + lo];
      part[((size_t)ssel * gridDim.y + blockIdx.y) * NOUT + n0 + cl] = v;
    }
    // full-line coalesced stores: 16 lanes cover one 256B row
#pragma unroll
    for (int p = 0; p < 8; ++p) {
      int rl = p * 16 + (tid >> 4), c8 = tid & 15;
      uint4 v = *(const uint4*)(ot + rl * 128 + ((c8 * 8) ^ (((rl >> 2) & 3) << 4)));
      *(uint4*)(outB + (size_t)(m0 + rl) * NOUT + n0 + c8 * 8) = v;
    }
  } else {
    // FINAL LDS is 2*SB*16 = 24576 B; stage the [64][128] f32 tile in two halves.
    float* otf = (float*)lds;
#pragma unroll
    for (int h = 0; h < 2; ++h) {
      __syncthreads();
#pragma unroll
      for (int c = 0; c < 4; ++c)
#pragma unroll
        for (int r = 0; r < RPW; ++r)
#pragma unroll
          for (int i = 0; i < 4; ++i) {
            int rl = rw + r * 16 + q * 4 + i;
            if ((rl >> 5) != h) continue;   // rows [h*32, h*32+32)
            int cl = cw + c * 16 + mr;
            otf[(rl - h * 32) * 128 + (cl ^ (((rl >> 2) & 3) << 4))] = acc[r][c][i];
          }
      __syncthreads();
#pragma unroll
      for (int p = 0; p < 4; ++p) {
        int rl = p * 8 + (tid >> 5), c4 = tid & 31;
        int rg = m0 + h * 32 + rl;
        if (rg < Mreal) {
          float4 v = *(const float4*)(otf + rl * 128 + ((c4 * 4) ^ ((((rl + h * 32) >> 2) & 3) << 4)));
          const float4 bv = *(const float4*)(bias + c4 * 4);
          v.x += bv.x; v.y += bv.y; v.z += bv.z; v.w += bv.w;
          *(float4*)(outF + (size_t)rg * 128 + c4 * 4) = v;
        }
      }
    }
  }
}

// ---------------- CSR aggregation (one wave per node) ----------------
template<int C, bool BN>
__global__ __launch_bounds__(256) void k_agg(const bf16* __restrict__ h,
                                             bf16* __restrict__ g,
                                             const int* __restrict__ csr,
                                             const int* __restrict__ roff,
                                             const float* __restrict__ dinv,
                                             const float* __restrict__ scale,
                                             const float* __restrict__ shift,
                                             int N) {
  constexpr int VPL = C / 64;   // channels per lane: 2 or 4
  const int lane = threadIdx.x & 63;
  const int v = (int)(((unsigned)blockIdx.x * 256 + threadIdx.x) >> 6);
  if (v >= N) return;
  float sc[VPL], sh[VPL];
  if constexpr (BN) {
#pragma unroll
    for (int u = 0; u < VPL; ++u) { sc[u] = scale[lane * VPL + u]; sh[u] = shift[lane * VPL + u]; }
  }
  const float dv = dinv[v];
  float acc[VPL];
#pragma unroll
  for (int u = 0; u < VPL; ++u) acc[u] = 0.f;

  auto accum = [&](int src, float w) {
    const bf16* hr = h + (size_t)src * C + lane * VPL;
    float vals[VPL];
    if constexpr (VPL == 2) {
      bf16x2 t = *(const bf16x2*)hr;
      vals[0] = (float)t[0]; vals[1] = (float)t[1];
    } else {
      bf16x4 t = *(const bf16x4*)hr;
#pragma unroll
      for (int u = 0; u < 4; ++u) vals[u] = (float)t[u];
    }
#pragma unroll
    for (int u = 0; u < VPL; ++u) {
      float xx = vals[u];
      if constexpr (BN) xx = fmaxf(0.f, xx * sc[u] + sh[u]);
      acc[u] += w * xx;
    }
  };

  accum(v, dv);   // self loop (becomes dv^2 after final *dv)
  const int beg = roff[v], end = roff[v + 1];
  for (int base = beg; base < end; base += 64) {
    int cnt = min(64, end - base);
    int s = 0; float w = 0.f;
    if (lane < cnt) { s = csr[base + lane]; w = dinv[s]; }
    for (int j = 0; j < cnt; ++j) {
      int sj = __shfl(s, j, 64);
      float wj = __shfl(w, j, 64);
      accum(sj, wj);
    }
  }

  bf16* gv = g + (size_t)v * C + lane * VPL;
  if constexpr (VPL == 2) {
    bf16x2 o;
    o[0] = (bf16)(acc[0] * dv); o[1] = (bf16)(acc[1] * dv);
    *(bf16x2*)gv = o;
  } else {
    bf16x4 o;
#pragma unroll
    for (int u = 0; u < 4; ++u) o[u] = (bf16)(acc[u] * dv);
    *(bf16x4*)gv = o;
  }
}

// ---------------- BatchNorm: reduce per-block partials + finalize ----------------
// part layout: [2][GX][C]; loads coalesced (64 lanes = 64 consecutive cols)
__global__ __launch_bounds__(256) void k_bnfinal(const float* __restrict__ part,
                                                 const float* __restrict__ gamma,
                                                 const float* __restrict__ beta,
                                                 float* __restrict__ scale,
                                                 float* __restrict__ shift,
                                                 int C, int GX, float invN) {
  __shared__ float red[2][4][64];
  int t = threadIdx.x;
  int cl = t & 63, seg = t >> 6;
  int c = blockIdx.x * 64 + cl;
  float s0 = 0.f, s1 = 0.f;
  for (int b = seg; b < GX; b += 4) {
    s0 += part[(size_t)b * C + c];
    s1 += part[(size_t)(GX + b) * C + c];
  }
  red[0][seg][cl] = s0; red[1][seg][cl] = s1;
  __syncthreads();
  if (seg == 0) {
    s0 = red[0][0][cl] + red[0][1][cl] + red[0][2][cl] + red[0][3][cl];
    s1 = red[1][0][cl] + red[1][1][cl] + red[1][2][cl] + red[1][3][cl];
    float mu = s0 * invN;
    float var = s1 * invN - mu * mu;   // biased var (ddof=0)
    float is = rsqrtf(var + 1e-5f);
    float scv = gamma[c] * is;
    scale[c] = scv;
    shift[c] = beta[c] - mu * scv;
  }
}

// in-place BN+ReLU, 8-wide (pad rows processed too: finite garbage, masked downstream)
template<int C>
__global__ void k_bnapply(bf16* __restrict__ g, const float* __restrict__ scale,
                          const float* __restrict__ shift, size_t total) {
  size_t base = ((size_t)blockIdx.x * 256 + threadIdx.x) * 8;
  if (base >= total) return;
  int col = (int)(base & (size_t)(C - 1));
  bf16x8 t = *(const bf16x8*)(g + base);
  bf16x8 o;
#pragma unroll
  for (int j = 0; j < 8; ++j)
    o[j] = (bf16)fmaxf(0.f, (float)t[j] * scale[col + j] + shift[col + j]);
  *(bf16x8*)(g + base) = o;
}

// ---------------- launch ----------------
extern "C" void kernel_launch(void* const* d_in, const int* in_sizes, int n_in,
                              void* d_out, int out_size, void* d_ws, size_t ws_size,
                              hipStream_t stream) {
  const float* x   = (const float*)d_in[0];
  const int*   ei  = (const int*)d_in[1];
  const float* W1  = (const float*)d_in[2];
  // d_in[3] = b1: absorbed by BN (mean subtraction cancels it)
  const float* g1  = (const float*)d_in[4];
  const float* be1 = (const float*)d_in[5];
  const float* W2  = (const float*)d_in[6];
  // d_in[7] = b2: absorbed by BN
  const float* g2  = (const float*)d_in[8];
  const float* be2 = (const float*)d_in[9];
  const float* Wl  = (const float*)d_in[10];
  const float* bl  = (const float*)d_in[11];
  float* out = (float*)d_out;

  const int N  = in_sizes[0] / 128;          // 50000
  const int E  = in_sizes[1] / 2;            // 500000
  const int Mp = ((N + 127) / 128) * 128;    // 50048 = 391*128 = 782*64
  const int NB = (N + 255) / 256;            // scan blocks (196)
  const int GX = Mp / 128;                   // 391 m-tiles (non-final)

  char* p = (char*)d_ws;
  auto carve = [&](size_t bytes) { void* r = (void*)p; p += (bytes + 255) & ~(size_t)255; return r; };
  int*   deg   = (int*)carve(sizeof(int) * N);
  int*   cur   = (int*)carve(sizeof(int) * N);
  int*   roff  = (int*)carve(sizeof(int) * (N + 1));
  int*   csr   = (int*)carve(sizeof(int) * E);
  int*   bsum  = (int*)carve(sizeof(int) * 256);
  int*   bpre  = (int*)carve(sizeof(int) * 256);
  float* dinv  = (float*)carve(sizeof(float) * N);
  float* part1 = (float*)carve(sizeof(float) * 2 * (size_t)GX * 256);
  float* part2 = (float*)carve(sizeof(float) * 2 * (size_t)GX * 512);
  float* sc1   = (float*)carve(sizeof(float) * 256);
  float* sh1   = (float*)carve(sizeof(float) * 256);
  float* sc2   = (float*)carve(sizeof(float) * 512);
  float* sh2   = (float*)carve(sizeof(float) * 512);
  bf16*  w1t   = (bf16*)carve(sizeof(bf16) * 256 * 128);
  bf16*  w2t   = (bf16*)carve(sizeof(bf16) * 512 * 256);
  bf16*  wlt   = (bf16*)carve(sizeof(bf16) * 128 * 512);
  bf16*  xb    = (bf16*)carve(sizeof(bf16) * (size_t)Mp * 128);
  bf16*  ax1   = (bf16*)carve(sizeof(bf16) * (size_t)Mp * 128);  // agg(x)
  bf16*  t1    = (bf16*)carve(sizeof(bf16) * (size_t)Mp * 256);  // ax1 @ W1
  bf16*  ax2   = (bf16*)carve(sizeof(bf16) * (size_t)Mp * 256);  // agg(relu(bn(t1)))
  bf16*  t2    = (bf16*)carve(sizeof(bf16) * (size_t)Mp * 512);  // ax2 @ W2, then bn+relu in place
  (void)n_in; (void)out_size; (void)ws_size;

  const int gE = (E + 255) / 256;
  k_init<<<NB, 256, 0, stream>>>(deg, cur, N);
  k_count<<<gE, 256, 0, stream>>>(ei, deg, E);
  k_scan1<<<NB, 256, 0, stream>>>(deg, bsum, N);
  k_scan2<<<1, 256, 0, stream>>>(bsum, bpre, NB);
  k_scan3<<<NB, 256, 0, stream>>>(deg, bpre, roff, dinv, N);   // dinv fused
  k_scatter<<<gE, 256, 0, stream>>>(ei, roff, cur, csr, E);

  k_cvt_x<<<(int)(((size_t)N * 128 / 4 + 255) / 256), 256, 0, stream>>>(x, xb, (size_t)N * 128);
  k_cvt_w<<<896, 256, 0, stream>>>(W1, W2, Wl, w1t, w2t, wlt);

  const int gAgg = (N + 3) / 4;
  // layer 1: aggregate first (S commutes with dense transform), then GEMM(+stats)
  k_agg<128, false><<<gAgg, 256, 0, stream>>>(xb, ax1, csr, roff, dinv, nullptr, nullptr, N);
  k_gemm<128, 256, false><<<dim3(2, GX), 256, 0, stream>>>(ax1, w1t, t1, nullptr, nullptr, part1, N);
  k_bnfinal<<<4, 256, 0, stream>>>(part1, g1, be1, sc1, sh1, 256, GX, 1.f / (float)N);

  // layer 2: gather applies BN1+ReLU on the fly
  k_agg<256, true><<<gAgg, 256, 0, stream>>>(t1, ax2, csr, roff, dinv, sc1, sh1, N);
  k_gemm<256, 512, false><<<dim3(4, GX), 256, 0, stream>>>(ax2, w2t, t2, nullptr, nullptr, part2, N);
  k_bnfinal<<<8, 256, 0, stream>>>(part2, g2, be2, sc2, sh2, 512, GX, 1.f / (float)N);
  k_bnapply<512><<<(int)(((size_t)Mp * 512 / 8 + 255) / 256), 256, 0, stream>>>(t2, sc2, sh2, (size_t)Mp * 512);

  // final linear: out = a2 @ Wl + bl (fp32 store, masked to real rows; 64-row tiles)
  k_gemm<512, 128, true><<<dim3(1, Mp / 64), 256, 0, stream>>>(t2, wlt, nullptr, out, bl, nullptr, N);
}

// Round 4
// 362.744 us; speedup vs baseline: 1.1446x; 1.1446x over previous
//
#include <hip/hip_runtime.h>
#include <cstdint>
#include <cstddef>

typedef __bf16 bf16;
typedef bf16 bf16x2 __attribute__((ext_vector_type(2)));
typedef bf16 bf16x4 __attribute__((ext_vector_type(4)));
typedef bf16 bf16x8 __attribute__((ext_vector_type(8)));
typedef float f32x4 __attribute__((ext_vector_type(4)));

// async global->LDS, 16B per lane; dest must be wave-uniform base (HW adds lane*16)
__device__ __forceinline__ void gll16(const void* g, void* l) {
  __builtin_amdgcn_global_load_lds((__attribute__((address_space(1))) void*)g,
                                   (__attribute__((address_space(3))) void*)l, 16, 0, 0);
}

// ---------------- graph preprocessing ----------------
__global__ void k_init(int* __restrict__ deg, int* __restrict__ cur, int N) {
  int i = blockIdx.x * 256 + threadIdx.x;
  if (i < N) { deg[i] = 1; cur[i] = 0; }   // deg starts at 1: self loop
}

__global__ void k_count(const int* __restrict__ ei, int* __restrict__ deg, int E) {
  int e = blockIdx.x * 256 + threadIdx.x;
  if (e < E) atomicAdd(&deg[ei[E + e]], 1);   // dst = ei[E+e]
}

__global__ __launch_bounds__(256) void k_scan1(const int* __restrict__ deg,
                                               int* __restrict__ bsum, int N) {
  int t = threadIdx.x;
  int i = blockIdx.x * 256 + t;
  int v = (i < N) ? deg[i] - 1 : 0;
#pragma unroll
  for (int off = 32; off > 0; off >>= 1) v += __shfl_down(v, off, 64);
  __shared__ int red[4];
  if ((t & 63) == 0) red[t >> 6] = v;
  __syncthreads();
  if (t == 0) bsum[blockIdx.x] = red[0] + red[1] + red[2] + red[3];
}

__global__ __launch_bounds__(256) void k_scan2(const int* __restrict__ bsum,
                                               int* __restrict__ bpre, int B) {
  __shared__ int s[256];
  int t = threadIdx.x;
  int v = (t < B) ? bsum[t] : 0;
  s[t] = v;
  __syncthreads();
  for (int off = 1; off < 256; off <<= 1) {
    int add = (t >= off) ? s[t - off] : 0;
    __syncthreads();
    s[t] += add;
    __syncthreads();
  }
  if (t < B) bpre[t] = s[t] - v;   // exclusive
}

__global__ __launch_bounds__(256) void k_scan3(const int* __restrict__ deg,
                                               const int* __restrict__ bpre,
                                               int* __restrict__ roff,
                                               float* __restrict__ dinv, int N) {
  __shared__ int s[256];
  int t = threadIdx.x;
  int i = blockIdx.x * 256 + t;
  int d = (i < N) ? deg[i] : 1;
  int v = d - 1;
  if (i >= N) v = 0;
  s[t] = v;
  __syncthreads();
  for (int off = 1; off < 256; off <<= 1) {
    int add = (t >= off) ? s[t - off] : 0;
    __syncthreads();
    s[t] += add;
    __syncthreads();
  }
  if (i < N) {
    int base = bpre[blockIdx.x];
    roff[i] = base + s[t] - v;
    dinv[i] = rsqrtf((float)d);
    if (i == N - 1) roff[N] = base + s[t];
  }
}

__global__ void k_scatter(const int* __restrict__ ei, const int* __restrict__ roff,
                          int* __restrict__ cur, int* __restrict__ csr, int E) {
  int e = blockIdx.x * 256 + threadIdx.x;
  if (e >= E) return;
  int d = ei[E + e];
  int p = atomicAdd(&cur[d], 1);
  csr[roff[d] + p] = ei[e];   // src
}

// ---------------- dtype conversion ----------------
__global__ void k_cvt_x(const float* __restrict__ x, bf16* __restrict__ xb, size_t total) {
  size_t base = ((size_t)blockIdx.x * 256 + threadIdx.x) * 4;
  if (base >= total) return;
  const float4 v = *(const float4*)(x + base);
  bf16x4 o;
  o[0] = (bf16)v.x; o[1] = (bf16)v.y; o[2] = (bf16)v.z; o[3] = (bf16)v.w;
  *(bf16x4*)(xb + base) = o;
}

__global__ void k_cvt_w(const float* __restrict__ W1, const float* __restrict__ W2,
                        const float* __restrict__ Wl, bf16* __restrict__ w1t,
                        bf16* __restrict__ w2t, bf16* __restrict__ wlt) {
  int i = blockIdx.x * 256 + threadIdx.x;   // grid covers 229376 exactly
  if (i < 32768) {
    int n = i >> 7, k = i & 127;
    w1t[i] = (bf16)W1[(size_t)k * 256 + n];
  } else if (i < 163840) {
    int j = i - 32768;
    int n = j >> 8, k = j & 255;
    w2t[j] = (bf16)W2[(size_t)k * 512 + n];
  } else {
    int j = i - 163840;
    int n = j >> 9, k = j & 511;
    wlt[j] = (bf16)Wl[(size_t)k * 128 + n];
  }
}

// ---------------- bf16 MFMA GEMM: C[M,NOUT] = A[M,K] @ Bt[NOUT,K]^T ----------------
// R12 = R11 with the DMA COALESCING fixed. R11's map (slot&(MT-1)=row) made
// consecutive lanes read consecutive ROWS (64 lines/instr, 16B used each) —
// 4x VMEM request rate; per-K-step cost was 3.4x m97's. New layout:
//   LDS granule(row, pos) = row*4 + pos, where pos holds chunk (pos^(row&3)).
//   DMA: slot=tid -> row=slot>>2, pos=slot&3 -> src chunk (pos^(row&3)):
//        4 consecutive lanes cover one row's full 64B (permuted in-line) =
//        line-coalesced, same request count as ideal.
//   Read: granule = row*4 + (q^(row&3)) -> 2-way bank conflict per 8-lane
//        phase (free per m136; m252: LDS reads not critical at 2-phase).
// Everything else (2-buffer m97 schedule, LDS-transpose epilogue, BN partials)
// unchanged from R11.
template<int K, int NOUT, bool FINAL>
__global__ __launch_bounds__(256, 4) void k_gemm(const bf16* __restrict__ A,
                                                 const bf16* __restrict__ Bt,
                                                 bf16* __restrict__ outB,
                                                 float* __restrict__ outF,
                                                 const float* __restrict__ bias,
                                                 float* __restrict__ part,
                                                 int Mreal) {
  constexpr int MT    = FINAL ? 64 : 128;   // m-tile rows
  constexpr int RPW   = MT / 32;            // 16-row subtiles per wave
  constexpr int NSTEP = K / 32;
  constexpr int SB    = MT * 4 + 512;       // uint4 slots per buffer (A + B)
  constexpr int NAI   = (MT * 4) / 256;     // A DMA issues per thread (2 or 1)
  __shared__ uint4 lds[2 * SB];
  __shared__ float sstm[512];               // stats scratch, DISJOINT from lds

  const int tid = threadIdx.x;
  const int wv = tid >> 6;
  const int lane = tid & 63;
  const int q = lane >> 4, mr = lane & 15;
  const int m0 = blockIdx.y * MT;
  const int n0 = blockIdx.x * 128;
  const int rw = (wv >> 1) * (MT / 2), cw = (wv & 1) * 64;
  const int wslot = wv << 6;
  const int qx = q ^ (mr & 3);   // read-side in-row XOR (row&3 == mr&3)

  // coalesced per-lane global sources: dest granule slot=p*256+tid (linear)
  // holds (row = slot>>2, chunk = (slot&3)^(row&3)) of the current K-step.
  const bf16* srcA[NAI];
#pragma unroll
  for (int p = 0; p < NAI; ++p) {
    int slot = p * 256 + tid;
    int row = slot >> 2;
    int c = (slot & 3) ^ (row & 3);
    srcA[p] = A + (size_t)(m0 + row) * K + c * 8;
  }
  const bf16* srcB[2];
#pragma unroll
  for (int p = 0; p < 2; ++p) {
    int slot = p * 256 + tid;
    int row = slot >> 2;
    int c = (slot & 3) ^ (row & 3);
    srcB[p] = Bt + (size_t)(n0 + row) * K + c * 8;
  }

  auto issue = [&](int t) {
    uint4* bb = lds + (t & 1) * SB;
#pragma unroll
    for (int p = 0; p < NAI; ++p)
      gll16(srcA[p] + t * 32, bb + p * 256 + wslot);
#pragma unroll
    for (int p = 0; p < 2; ++p)
      gll16(srcB[p] + t * 32, bb + MT * 4 + p * 256 + wslot);
  };

  f32x4 acc[RPW][4];
#pragma unroll
  for (int r = 0; r < RPW; ++r)
#pragma unroll
    for (int c = 0; c < 4; ++c) acc[r][c] = (f32x4){0.f, 0.f, 0.f, 0.f};

  issue(0);
  __syncthreads();   // drains DMA: buf 0 ready

#pragma unroll
  for (int t = 0; t < NSTEP; ++t) {
    if (t + 1 < NSTEP) issue(t + 1);   // in flight across the compute phase

    const uint4* bb = lds + (t & 1) * SB;
    const bf16x8* bA = (const bf16x8*)bb;
    const bf16x8* bB = (const bf16x8*)(bb + MT * 4);
    bf16x8 bfr[4];
#pragma unroll
    for (int c = 0; c < 4; ++c) {
      int rb = cw + c * 16 + mr;
      bfr[c] = bB[rb * 4 + qx];
    }
#pragma unroll
    for (int r = 0; r < RPW; ++r) {
      int ra = rw + r * 16 + mr;
      bf16x8 af = bA[ra * 4 + qx];
#pragma unroll
      for (int c = 0; c < 4; ++c)
        acc[r][c] = __builtin_amdgcn_mfma_f32_16x16x32_bf16(af, bfr[c], acc[r][c], 0, 0, 0);
    }
    __syncthreads();   // drains next tile's DMA (after compute) + read fence
  }

  // C/D layout: col = lane&15, row = (lane>>4)*4 + reg (m89/m91-verified)
  if constexpr (!FINAL) {
    bf16* ot = (bf16*)lds;                  // [128][128] bf16, XOR-swizzled cols
#pragma unroll
    for (int c = 0; c < 4; ++c) {
      float s0 = 0.f, s1 = 0.f;
#pragma unroll
      for (int r = 0; r < RPW; ++r) {
#pragma unroll
        for (int i = 0; i < 4; ++i) {
          int rl = rw + r * 16 + q * 4 + i;
          int cl = cw + c * 16 + mr;
          float v = acc[r][c][i];
          ot[rl * 128 + (cl ^ (((rl >> 2) & 3) << 4))] = (bf16)v;
          if (m0 + rl < Mreal) { s0 += v; s1 += v * v; }
        }
      }
      s0 += __shfl_xor(s0, 16, 64); s0 += __shfl_xor(s0, 32, 64);
      s1 += __shfl_xor(s1, 16, 64); s1 += __shfl_xor(s1, 32, 64);
      if (q == 0) {
        sstm[wv * 64 + c * 16 + mr] = s0;
        sstm[256 + wv * 64 + c * 16 + mr] = s1;
      }
    }
    __syncthreads();
    {
      // combine wave pairs, plain-store per-block partials (no atomics)
      int ssel = tid >> 7, cl = tid & 127;
      int hi = cl >> 6, lo = cl & 63;
      float v = sstm[ssel * 256 + hi * 64 + lo] + sstm[ssel * 256 + (hi + 2) * 64 + lo];
      part[((size_t)ssel * gridDim.y + blockIdx.y) * NOUT + n0 + cl] = v;
    }
    // full-line coalesced stores: 16 lanes cover one 256B row
#pragma unroll
    for (int p = 0; p < 8; ++p) {
      int rl = p * 16 + (tid >> 4), c8 = tid & 15;
      uint4 v = *(const uint4*)(ot + rl * 128 + ((c8 * 8) ^ (((rl >> 2) & 3) << 4)));
      *(uint4*)(outB + (size_t)(m0 + rl) * NOUT + n0 + c8 * 8) = v;
    }
  } else {
    // FINAL LDS is 2*SB*16 = 24576 B; stage the [64][128] f32 tile in two halves.
    float* otf = (float*)lds;
#pragma unroll
    for (int h = 0; h < 2; ++h) {
      __syncthreads();
#pragma unroll
      for (int c = 0; c < 4; ++c)
#pragma unroll
        for (int r = 0; r < RPW; ++r)
#pragma unroll
          for (int i = 0; i < 4; ++i) {
            int rl = rw + r * 16 + q * 4 + i;
            if ((rl >> 5) != h) continue;   // rows [h*32, h*32+32)
            int cl = cw + c * 16 + mr;
            otf[(rl - h * 32) * 128 + (cl ^ (((rl >> 2) & 3) << 4))] = acc[r][c][i];
          }
      __syncthreads();
#pragma unroll
      for (int p = 0; p < 4; ++p) {
        int rl = p * 8 + (tid >> 5), c4 = tid & 31;
        int rg = m0 + h * 32 + rl;
        if (rg < Mreal) {
          float4 v = *(const float4*)(otf + rl * 128 + ((c4 * 4) ^ ((((rl + h * 32) >> 2) & 3) << 4)));
          const float4 bv = *(const float4*)(bias + c4 * 4);
          v.x += bv.x; v.y += bv.y; v.z += bv.z; v.w += bv.w;
          *(float4*)(outF + (size_t)rg * 128 + c4 * 4) = v;
        }
      }
    }
  }
}

// ---------------- CSR aggregation (one wave per node) ----------------
// R12: edge loop unrolled x4 — four independent row-gathers in flight per
// wave (R11 had 1; VGPR_Count=20 showed the compiler had no ILP to work with).
template<int C, bool BN>
__global__ __launch_bounds__(256) void k_agg(const bf16* __restrict__ h,
                                             bf16* __restrict__ g,
                                             const int* __restrict__ csr,
                                             const int* __restrict__ roff,
                                             const float* __restrict__ dinv,
                                             const float* __restrict__ scale,
                                             const float* __restrict__ shift,
                                             int N) {
  constexpr int VPL = C / 64;   // channels per lane: 2 or 4
  const int lane = threadIdx.x & 63;
  const int v = (int)(((unsigned)blockIdx.x * 256 + threadIdx.x) >> 6);
  if (v >= N) return;
  float sc[VPL], sh[VPL];
  if constexpr (BN) {
#pragma unroll
    for (int u = 0; u < VPL; ++u) { sc[u] = scale[lane * VPL + u]; sh[u] = shift[lane * VPL + u]; }
  }
  const float dv = dinv[v];
  float acc[VPL];
#pragma unroll
  for (int u = 0; u < VPL; ++u) acc[u] = 0.f;

  auto loadrow = [&](int src, float* o) {
    const bf16* hr = h + (size_t)src * C + lane * VPL;
    if constexpr (VPL == 2) {
      bf16x2 t = *(const bf16x2*)hr;
      o[0] = (float)t[0]; o[1] = (float)t[1];
    } else {
      bf16x4 t = *(const bf16x4*)hr;
#pragma unroll
      for (int u = 0; u < 4; ++u) o[u] = (float)t[u];
    }
  };
  auto addrow = [&](const float* vv, float ww) {
#pragma unroll
    for (int u = 0; u < VPL; ++u) {
      float xx = vv[u];
      if constexpr (BN) xx = fmaxf(0.f, xx * sc[u] + sh[u]);
      acc[u] += ww * xx;
    }
  };

  {   // self loop (becomes dv^2 after final *dv)
    float vv[VPL];
    loadrow(v, vv);
    addrow(vv, dv);
  }
  const int beg = roff[v], end = roff[v + 1];
  for (int base = beg; base < end; base += 64) {
    int cnt = min(64, end - base);
    int s = 0; float w = 0.f;
    if (lane < cnt) { s = csr[base + lane]; w = dinv[s]; }
    int j = 0;
    for (; j + 4 <= cnt; j += 4) {
      int sa = __shfl(s, j, 64),     sb = __shfl(s, j + 1, 64);
      int sc2 = __shfl(s, j + 2, 64), sd = __shfl(s, j + 3, 64);
      float wa = __shfl(w, j, 64),     wb = __shfl(w, j + 1, 64);
      float wc = __shfl(w, j + 2, 64), wd = __shfl(w, j + 3, 64);
      float va[VPL], vb[VPL], vc[VPL], vd[VPL];
      loadrow(sa, va); loadrow(sb, vb); loadrow(sc2, vc); loadrow(sd, vd);
      addrow(va, wa); addrow(vb, wb); addrow(vc, wc); addrow(vd, wd);
    }
    for (; j < cnt; ++j) {
      int sj = __shfl(s, j, 64);
      float wj = __shfl(w, j, 64);
      float vv[VPL];
      loadrow(sj, vv);
      addrow(vv, wj);
    }
  }

  bf16* gv = g + (size_t)v * C + lane * VPL;
  if constexpr (VPL == 2) {
    bf16x2 o;
    o[0] = (bf16)(acc[0] * dv); o[1] = (bf16)(acc[1] * dv);
    *(bf16x2*)gv = o;
  } else {
    bf16x4 o;
#pragma unroll
    for (int u = 0; u < 4; ++u) o[u] = (bf16)(acc[u] * dv);
    *(bf16x4*)gv = o;
  }
}

// ---------------- BatchNorm: reduce per-block partials + finalize ----------------
// part layout: [2][GX][C]; loads coalesced (64 lanes = 64 consecutive cols)
__global__ __launch_bounds__(256) void k_bnfinal(const float* __restrict__ part,
                                                 const float* __restrict__ gamma,
                                                 const float* __restrict__ beta,
                                                 float* __restrict__ scale,
                                                 float* __restrict__ shift,
                                                 int C, int GX, float invN) {
  __shared__ float red[2][4][64];
  int t = threadIdx.x;
  int cl = t & 63, seg = t >> 6;
  int c = blockIdx.x * 64 + cl;
  float s0 = 0.f, s1 = 0.f;
  for (int b = seg; b < GX; b += 4) {
    s0 += part[(size_t)b * C + c];
    s1 += part[(size_t)(GX + b) * C + c];
  }
  red[0][seg][cl] = s0; red[1][seg][cl] = s1;
  __syncthreads();
  if (seg == 0) {
    s0 = red[0][0][cl] + red[0][1][cl] + red[0][2][cl] + red[0][3][cl];
    s1 = red[1][0][cl] + red[1][1][cl] + red[1][2][cl] + red[1][3][cl];
    float mu = s0 * invN;
    float var = s1 * invN - mu * mu;   // biased var (ddof=0)
    float is = rsqrtf(var + 1e-5f);
    float scv = gamma[c] * is;
    scale[c] = scv;
    shift[c] = beta[c] - mu * scv;
  }
}

// in-place BN+ReLU, 8-wide (pad rows processed too: finite garbage, masked downstream)
template<int C>
__global__ void k_bnapply(bf16* __restrict__ g, const float* __restrict__ scale,
                          const float* __restrict__ shift, size_t total) {
  size_t base = ((size_t)blockIdx.x * 256 + threadIdx.x) * 8;
  if (base >= total) return;
  int col = (int)(base & (size_t)(C - 1));
  bf16x8 t = *(const bf16x8*)(g + base);
  bf16x8 o;
#pragma unroll
  for (int j = 0; j < 8; ++j)
    o[j] = (bf16)fmaxf(0.f, (float)t[j] * scale[col + j] + shift[col + j]);
  *(bf16x8*)(g + base) = o;
}

// ---------------- launch ----------------
extern "C" void kernel_launch(void* const* d_in, const int* in_sizes, int n_in,
                              void* d_out, int out_size, void* d_ws, size_t ws_size,
                              hipStream_t stream) {
  const float* x   = (const float*)d_in[0];
  const int*   ei  = (const int*)d_in[1];
  const float* W1  = (const float*)d_in[2];
  // d_in[3] = b1: absorbed by BN (mean subtraction cancels it)
  const float* g1  = (const float*)d_in[4];
  const float* be1 = (const float*)d_in[5];
  const float* W2  = (const float*)d_in[6];
  // d_in[7] = b2: absorbed by BN
  const float* g2  = (const float*)d_in[8];
  const float* be2 = (const float*)d_in[9];
  const float* Wl  = (const float*)d_in[10];
  const float* bl  = (const float*)d_in[11];
  float* out = (float*)d_out;

  const int N  = in_sizes[0] / 128;          // 50000
  const int E  = in_sizes[1] / 2;            // 500000
  const int Mp = ((N + 127) / 128) * 128;    // 50048 = 391*128 = 782*64
  const int NB = (N + 255) / 256;            // scan blocks (196)
  const int GX = Mp / 128;                   // 391 m-tiles (non-final)

  char* p = (char*)d_ws;
  auto carve = [&](size_t bytes) { void* r = (void*)p; p += (bytes + 255) & ~(size_t)255; return r; };
  int*   deg   = (int*)carve(sizeof(int) * N);
  int*   cur   = (int*)carve(sizeof(int) * N);
  int*   roff  = (int*)carve(sizeof(int) * (N + 1));
  int*   csr   = (int*)carve(sizeof(int) * E);
  int*   bsum  = (int*)carve(sizeof(int) * 256);
  int*   bpre  = (int*)carve(sizeof(int) * 256);
  float* dinv  = (float*)carve(sizeof(float) * N);
  float* part1 = (float*)carve(sizeof(float) * 2 * (size_t)GX * 256);
  float* part2 = (float*)carve(sizeof(float) * 2 * (size_t)GX * 512);
  float* sc1   = (float*)carve(sizeof(float) * 256);
  float* sh1   = (float*)carve(sizeof(float) * 256);
  float* sc2   = (float*)carve(sizeof(float) * 512);
  float* sh2   = (float*)carve(sizeof(float) * 512);
  bf16*  w1t   = (bf16*)carve(sizeof(bf16) * 256 * 128);
  bf16*  w2t   = (bf16*)carve(sizeof(bf16) * 512 * 256);
  bf16*  wlt   = (bf16*)carve(sizeof(bf16) * 128 * 512);
  bf16*  xb    = (bf16*)carve(sizeof(bf16) * (size_t)Mp * 128);
  bf16*  ax1   = (bf16*)carve(sizeof(bf16) * (size_t)Mp * 128);  // agg(x)
  bf16*  t1    = (bf16*)carve(sizeof(bf16) * (size_t)Mp * 256);  // ax1 @ W1
  bf16*  ax2   = (bf16*)carve(sizeof(bf16) * (size_t)Mp * 256);  // agg(relu(bn(t1)))
  bf16*  t2    = (bf16*)carve(sizeof(bf16) * (size_t)Mp * 512);  // ax2 @ W2, then bn+relu in place
  (void)n_in; (void)out_size; (void)ws_size;

  const int gE = (E + 255) / 256;
  k_init<<<NB, 256, 0, stream>>>(deg, cur, N);
  k_count<<<gE, 256, 0, stream>>>(ei, deg, E);
  k_scan1<<<NB, 256, 0, stream>>>(deg, bsum, N);
  k_scan2<<<1, 256, 0, stream>>>(bsum, bpre, NB);
  k_scan3<<<NB, 256, 0, stream>>>(deg, bpre, roff, dinv, N);   // dinv fused
  k_scatter<<<gE, 256, 0, stream>>>(ei, roff, cur, csr, E);

  k_cvt_x<<<(int)(((size_t)N * 128 / 4 + 255) / 256), 256, 0, stream>>>(x, xb, (size_t)N * 128);
  k_cvt_w<<<896, 256, 0, stream>>>(W1, W2, Wl, w1t, w2t, wlt);

  const int gAgg = (N + 3) / 4;
  // layer 1: aggregate first (S commutes with dense transform), then GEMM(+stats)
  k_agg<128, false><<<gAgg, 256, 0, stream>>>(xb, ax1, csr, roff, dinv, nullptr, nullptr, N);
  k_gemm<128, 256, false><<<dim3(2, GX), 256, 0, stream>>>(ax1, w1t, t1, nullptr, nullptr, part1, N);
  k_bnfinal<<<4, 256, 0, stream>>>(part1, g1, be1, sc1, sh1, 256, GX, 1.f / (float)N);

  // layer 2: gather applies BN1+ReLU on the fly
  k_agg<256, true><<<gAgg, 256, 0, stream>>>(t1, ax2, csr, roff, dinv, sc1, sh1, N);
  k_gemm<256, 512, false><<<dim3(4, GX), 256, 0, stream>>>(ax2, w2t, t2, nullptr, nullptr, part2, N);
  k_bnfinal<<<8, 256, 0, stream>>>(part2, g2, be2, sc2, sh2, 512, GX, 1.f / (float)N);
  k_bnapply<512><<<(int)(((size_t)Mp * 512 / 8 + 255) / 256), 256, 0, stream>>>(t2, sc2, sh2, (size_t)Mp * 512);

  // final linear: out = a2 @ Wl + bl (fp32 store, masked to real rows; 64-row tiles)
  k_gemm<512, 128, true><<<dim3(1, Mp / 64), 256, 0, stream>>>(t2, wlt, nullptr, out, bl, nullptr, N);
}